// Round 3
// baseline (446.577 us; speedup 1.0000x reference)
//
#include <hip/hip_runtime.h>
#include <math.h>

// ForwardKinematics: B=524288, J=24, fp32.
// v4: wave-local transpose staging -> ZERO block barriers, zero-tail grid.
// v3 post-mortem: traffic is near-ideal (389MB vs 417MB ideal) but BW only
// 2.5 TB/s. Two structural costs: (1) __syncthreads drains vmcnt(0), so each
// chunk's global stores serialized into block lifetime (3x per block);
// (2) grid 2048 at 6 blocks/CU residency -> 1.33 dispatch rounds, 33% of work
// at 1/3 width (matches 37% time-avg occupancy).
// Fix: transpose only needs to cross lanes WITHIN a wave. Each wave owns 64
// elements, stages 4-joint chunks in a private [12][65] LDS tile (3.1KB/wave,
// 12.5KB/block). Wave-sync LDS needs only s_waitcnt lgkmcnt(0) (inline asm),
// no s_barrier -> stores pipeline freely. Grid 1024 x 2 tiles/block is fully
// co-resident for any residency >=4 blocks/CU -> one balanced round, no tail.

#define NB 524288
#define NJ 24
#define BLOCK 256
#define TILES 2
#define NGRID (NB / (BLOCK * TILES))   // 1024
#define CH 4                            // joints per chunk
#define NCH (NJ / CH)                   // 6
#define ROWS (CH * 3)                   // 12
#define LSTR 65                         // 64 cols + 1 pad: bank = (row+col)%32

namespace {
constexpr int PAR[NJ] = {-1,0,0,0,1,2,3,4,5,6,7,8,9,9,9,12,13,14,16,17,18,19,20,21};
}

__global__ __launch_bounds__(BLOCK)
void ForwardKinematics_51342039056994_kernel(
    const float* __restrict__ root_q,   // (B,4)
    const float* __restrict__ root_p,   // (B,3)
    const float* __restrict__ loc_q,    // (B,24,4)
    const float* __restrict__ bones,    // (B,24)
    const float* __restrict__ rest_d,   // (24,3) uniform -> scalar loads
    float* __restrict__ out)            // (B,24,3)
{
    __shared__ float lds[4][ROWS * LSTR];   // per-wave private tiles, 12480 B total

    const int tid  = threadIdx.x;
    const int lane = tid & 63;
    const int wid  = tid >> 6;
    float* wlds = lds[wid];

    float4* outv = (float4*)out;

    #define DO_JOINT(j, lqv, L)                                                 \
    {                                                                           \
        const int p_ = PAR[(j)];                                                \
        float lw = (lqv).x, lx = (lqv).y, ly = (lqv).z, lz = (lqv).w;           \
        float invn = 1.0f / (sqrtf(lw*lw + lx*lx + ly*ly + lz*lz) + 1e-8f);     \
        lw *= invn; lx *= invn; ly *= invn; lz *= invn;                         \
        const float pw  = gqw[p_], px_ = gqx[p_], py_ = gqy[p_], pz_ = gqz[p_]; \
        gqw[(j)] = pw*lw - px_*lx - py_*ly - pz_*lz;                            \
        gqx[(j)] = pw*lx + px_*lw + py_*lz - pz_*ly;                            \
        gqy[(j)] = pw*ly - px_*lz + py_*lw + pz_*lx;                            \
        gqz[(j)] = pw*lz + px_*ly - py_*lx + pz_*lw;                            \
        const float dx = rest_d[3*(j)+0];                                       \
        const float dy = rest_d[3*(j)+1];                                       \
        const float dz = rest_d[3*(j)+2];                                       \
        float tx = 2.0f*(py_*dz - pz_*dy);                                      \
        float ty = 2.0f*(pz_*dx - px_*dz);                                      \
        float tz = 2.0f*(px_*dy - py_*dx);                                      \
        float rx = dx + pw*tx + (py_*tz - pz_*ty);                              \
        float ry = dy + pw*ty + (pz_*tx - px_*tz);                              \
        float rz = dz + pw*tz + (px_*ty - py_*tx);                              \
        gpx[(j)] = gpx[p_] + rx*(L);                                            \
        gpy[(j)] = gpy[p_] + ry*(L);                                            \
        gpz[(j)] = gpz[p_] + rz*(L);                                            \
    }

    #pragma unroll 1
    for (int tile = 0; tile < TILES; ++tile) {
        const int waveBase = (blockIdx.x * TILES + tile) * BLOCK + wid * 64;
        const int b = waveBase + lane;

        float gqw[NJ], gqx[NJ], gqy[NJ], gqz[NJ];
        float gpx[NJ], gpy[NJ], gpz[NJ];

        // ---- root inputs ----
        float4 rq = ((const float4*)root_q)[b];
        float rpx = root_p[b*3+0], rpy = root_p[b*3+1], rpz = root_p[b*3+2];
        {
            float inv = 1.0f / (sqrtf(rq.x*rq.x + rq.y*rq.y + rq.z*rq.z + rq.w*rq.w) + 1e-8f);
            gqw[0] = rq.x * inv; gqx[0] = rq.y * inv; gqy[0] = rq.z * inv; gqz[0] = rq.w * inv;
        }
        gpx[0] = rpx; gpy[0] = rpy; gpz[0] = rpz;

        const float4* lsrc = (const float4*)loc_q + (size_t)b * NJ;   // 24 float4/elem
        const float4* bsrc = (const float4*)(bones + (size_t)b * NJ); // 6 float4/elem

        // ---- prefetch chunk 0 ----
        float4 lq[CH];
        #pragma unroll
        for (int i = 0; i < CH; ++i) lq[i] = lsrc[i];
        float4 bq = bsrc[0];

        #pragma unroll
        for (int c = 0; c < NCH; ++c) {
            // prefetch chunk c+1 (hidden under compute + store of chunk c)
            float4 nlq[CH]; float4 nbq;
            if (c < NCH - 1) {
                #pragma unroll
                for (int i = 0; i < CH; ++i) nlq[i] = lsrc[CH*(c+1) + i];
                nbq = bsrc[c+1];
            }

            float bl[CH] = {bq.x, bq.y, bq.z, bq.w};

            // ---- compute CH joints, stage positions: row = jj*3+comp, col = lane ----
            #pragma unroll
            for (int jj = 0; jj < CH; ++jj) {
                const int j = CH*c + jj;
                if (j > 0) DO_JOINT(j, lq[jj], bl[jj]);
                wlds[(jj*3 + 0) * LSTR + lane] = gpx[j];
                wlds[(jj*3 + 1) * LSTR + lane] = gpy[j];
                wlds[(jj*3 + 2) * LSTR + lane] = gpz[j];
            }

            // wave-synchronous: all lanes' ds_writes complete, no s_barrier
            asm volatile("s_waitcnt lgkmcnt(0)" ::: "memory");
            __builtin_amdgcn_sched_barrier(0);

            // ---- cooperative store: 64 elems * 12 floats = 192 float4, 3/lane.
            // Element t's chunk bytes: 48B contiguous at (waveBase+t)*288 + c*48. ----
            #pragma unroll
            for (int m = 0; m < 3; ++m) {
                int g = m * 64 + lane;
                int t = g / 3;
                int k = g - 3 * t;          // 0..2
                float4 v;
                v.x = wlds[(4*k + 0) * LSTR + t];
                v.y = wlds[(4*k + 1) * LSTR + t];
                v.z = wlds[(4*k + 2) * LSTR + t];
                v.w = wlds[(4*k + 3) * LSTR + t];
                outv[(size_t)(waveBase + t) * 18 + c * 3 + k] = v;
            }

            // keep next chunk's ds_writes from being hoisted above these ds_reads
            asm volatile("" ::: "memory");

            if (c < NCH - 1) {
                #pragma unroll
                for (int i = 0; i < CH; ++i) lq[i] = nlq[i];
                bq = nbq;
            }
        }
    }
    #undef DO_JOINT
}

extern "C" void kernel_launch(void* const* d_in, const int* in_sizes, int n_in,
                              void* d_out, int out_size, void* d_ws, size_t ws_size,
                              hipStream_t stream) {
    (void)in_sizes; (void)n_in; (void)out_size; (void)d_ws; (void)ws_size;
    const float* root_q = (const float*)d_in[0];
    const float* root_p = (const float*)d_in[1];
    const float* loc_q  = (const float*)d_in[2];
    const float* bones  = (const float*)d_in[3];
    const float* rest_d = (const float*)d_in[4];
    float* out = (float*)d_out;

    dim3 grid(NGRID);
    dim3 block(BLOCK);
    ForwardKinematics_51342039056994_kernel<<<grid, block, 0, stream>>>(
        root_q, root_p, loc_q, bones, rest_d, out);
}

// Round 4
// 366.239 us; speedup vs baseline: 1.2194x; 1.2194x over previous
//
#include <hip/hip_runtime.h>
#include <math.h>

// ForwardKinematics: B=524288, J=24, fp32.
// v5: wave-private FULL-record staging -> dense 288B/elem stores, zero barriers.
// v4 post-mortem: 48B wave-local store runs free-running across chunks left
// partial 64B lines in L2 that evicted before completion -> +59MB RFO fetch,
// +47MB writeback (497MB total vs 417 ideal). v3's 96B runs merged only
// because barriers paced whole-block phases tightly in time.
// Fix: stage ALL 24 joints' positions in a wave-private [72][65] f32 tile
// (18,720B), then ONE store phase per wave: 64 elems x 288B = 18,432B fully
// contiguous, every 64B line completely covered by same-phase stores.
// -> zero RFO, no dependence on L2 merge timing, and zero s_barrier
// (one wave per block; wave-private LDS ordered by compiler lgkmcnt).
// 18.7KB/block -> 8 blocks/CU = 2 waves/SIMD; issue-side needs ~9us total vs
// 66us memory floor, and 8 waves x ~24 outstanding 1KB loads >> in-flight
// bytes needed to saturate HBM at this CU's share.

#define NB 524288
#define NJ 24
#define BLOCK 64
#define ROWS 72     // 24 joints * 3 components; row = 3*j + comp
#define LSTR 65     // 64 cols + 1 pad: bank = (row + col) % 32

namespace {
constexpr int PAR[NJ] = {-1,0,0,0,1,2,3,4,5,6,7,8,9,9,9,12,13,14,16,17,18,19,20,21};
}

__global__ __launch_bounds__(BLOCK)
void ForwardKinematics_51342039056994_kernel(
    const float* __restrict__ root_q,   // (B,4)
    const float* __restrict__ root_p,   // (B,3)
    const float* __restrict__ loc_q,    // (B,24,4)
    const float* __restrict__ bones,    // (B,24)
    const float* __restrict__ rest_d,   // (24,3) uniform -> scalar loads
    float* __restrict__ out)            // (B,24,3)
{
    __shared__ float wlds[ROWS * LSTR];   // 18,720 B, wave-private (1 wave/block)

    const int lane = threadIdx.x;          // 0..63
    const int waveBase = blockIdx.x * BLOCK;
    const int b = waveBase + lane;

    float gqw[NJ], gqx[NJ], gqy[NJ], gqz[NJ];
    float gpx[NJ], gpy[NJ], gpz[NJ];

    // ---- root inputs (coalesced float4 quat + 3 dwords position) ----
    float4 rq = ((const float4*)root_q)[b];
    float rpx = root_p[b*3+0], rpy = root_p[b*3+1], rpz = root_p[b*3+2];
    {
        float inv = 1.0f / (sqrtf(rq.x*rq.x + rq.y*rq.y + rq.z*rq.z + rq.w*rq.w) + 1e-8f);
        gqw[0] = rq.x * inv; gqx[0] = rq.y * inv; gqy[0] = rq.z * inv; gqz[0] = rq.w * inv;
    }
    gpx[0] = rpx; gpy[0] = rpy; gpz[0] = rpz;
    wlds[0 * LSTR + lane] = rpx;
    wlds[1 * LSTR + lane] = rpy;
    wlds[2 * LSTR + lane] = rpz;

    const float4* lsrc = (const float4*)loc_q + (size_t)b * NJ;   // 24 float4/elem
    const float4* bsrc = (const float4*)(bones + (size_t)b * NJ); // 6 float4/elem

    #define DO_JOINT(j, lqv, L)                                                 \
    {                                                                           \
        const int p_ = PAR[(j)];                                                \
        float lw = (lqv).x, lx = (lqv).y, ly = (lqv).z, lz = (lqv).w;           \
        float invn = 1.0f / (sqrtf(lw*lw + lx*lx + ly*ly + lz*lz) + 1e-8f);     \
        lw *= invn; lx *= invn; ly *= invn; lz *= invn;                         \
        const float pw  = gqw[p_], px_ = gqx[p_], py_ = gqy[p_], pz_ = gqz[p_]; \
        gqw[(j)] = pw*lw - px_*lx - py_*ly - pz_*lz;                            \
        gqx[(j)] = pw*lx + px_*lw + py_*lz - pz_*ly;                            \
        gqy[(j)] = pw*ly - px_*lz + py_*lw + pz_*lx;                            \
        gqz[(j)] = pw*lz + px_*ly - py_*lx + pz_*lw;                            \
        const float dx = rest_d[3*(j)+0];                                       \
        const float dy = rest_d[3*(j)+1];                                       \
        const float dz = rest_d[3*(j)+2];                                       \
        float tx = 2.0f*(py_*dz - pz_*dy);                                      \
        float ty = 2.0f*(pz_*dx - px_*dz);                                      \
        float tz = 2.0f*(px_*dy - py_*dx);                                      \
        float rx = dx + pw*tx + (py_*tz - pz_*ty);                              \
        float ry = dy + pw*ty + (pz_*tx - px_*tz);                              \
        float rz = dz + pw*tz + (px_*ty - py_*tx);                              \
        gpx[(j)] = gpx[p_] + rx*(L);                                            \
        gpy[(j)] = gpy[p_] + ry*(L);                                            \
        gpz[(j)] = gpz[p_] + rz*(L);                                            \
        wlds[(3*(j) + 0) * LSTR + lane] = gpx[(j)];                             \
        wlds[(3*(j) + 1) * LSTR + lane] = gpy[(j)];                             \
        wlds[(3*(j) + 2) * LSTR + lane] = gpz[(j)];                             \
    }

    // ---- chunked compute with next-chunk prefetch (3 chunks of 8 joints) ----
    float4 lq[8];
    #pragma unroll
    for (int i = 0; i < 8; ++i) lq[i] = lsrc[i];
    float4 bq0 = bsrc[0], bq1 = bsrc[1];

    #pragma unroll
    for (int c = 0; c < 3; ++c) {
        float4 nlq[8]; float4 nb0, nb1;
        if (c < 2) {
            #pragma unroll
            for (int i = 0; i < 8; ++i) nlq[i] = lsrc[8*(c+1) + i];
            nb0 = bsrc[2*(c+1) + 0];
            nb1 = bsrc[2*(c+1) + 1];
        }

        float bl[8] = {bq0.x, bq0.y, bq0.z, bq0.w, bq1.x, bq1.y, bq1.z, bq1.w};

        #pragma unroll
        for (int jj = 0; jj < 8; ++jj) {
            const int j = 8*c + jj;
            if (j > 0) DO_JOINT(j, lq[jj], bl[jj]);
        }

        if (c < 2) {
            #pragma unroll
            for (int i = 0; i < 8; ++i) lq[i] = nlq[i];
            bq0 = nb0; bq1 = nb1;
        }
    }
    #undef DO_JOINT

    // ---- single dense store phase: 64 elems * 18 float4 = 1152 float4,
    // 18 per lane, consecutive g -> wave covers 18,432B contiguous at
    // waveBase*288 (64B-aligned). Every HBM line fully covered. ----
    // Compiler inserts lgkmcnt ordering for the ds_write->ds_read dependency;
    // tile is wave-private so no s_barrier is needed anywhere.
    float4* outv = (float4*)out + (size_t)waveBase * 18;
    #pragma unroll
    for (int m = 0; m < 18; ++m) {
        int g = m * 64 + lane;
        int t = g / 18;            // element column 0..63
        int k = g - 18 * t;        // float4 index 0..17 within record
        float4 v;
        v.x = wlds[(4*k + 0) * LSTR + t];
        v.y = wlds[(4*k + 1) * LSTR + t];
        v.z = wlds[(4*k + 2) * LSTR + t];
        v.w = wlds[(4*k + 3) * LSTR + t];
        outv[g] = v;
    }
}

extern "C" void kernel_launch(void* const* d_in, const int* in_sizes, int n_in,
                              void* d_out, int out_size, void* d_ws, size_t ws_size,
                              hipStream_t stream) {
    (void)in_sizes; (void)n_in; (void)out_size; (void)d_ws; (void)ws_size;
    const float* root_q = (const float*)d_in[0];
    const float* root_p = (const float*)d_in[1];
    const float* loc_q  = (const float*)d_in[2];
    const float* bones  = (const float*)d_in[3];
    const float* rest_d = (const float*)d_in[4];
    float* out = (float*)d_out;

    dim3 grid(NB / BLOCK);
    dim3 block(BLOCK);
    ForwardKinematics_51342039056994_kernel<<<grid, block, 0, stream>>>(
        root_q, root_p, loc_q, bones, rest_d, out);
}